// Round 13
// baseline (1100.401 us; speedup 1.0000x reference)
//
#include <hip/hip_runtime.h>
#include <hip/hip_bf16.h>
#include <hip/hip_fp16.h>
#include <math.h>

#define DH 10      // hidden dim
#define DE 3       // edge attr dim
#define DIN 3      // input dim
#define REC 20     // fp32 D record: 20 floats = 80B
#define SHU 16     // fp16 S record stride in uints: 64B-ALIGNED (10 used) -> 1 line/record
#define VEC 4      // lanes cooperating per node in gather
#define SSH 15     // slice shift
#define NS 6       // slices 0..5 (slice 5 merged tail); slice = 32768*64B = 2MB (L2-resident)
#define WGN 1024   // persistent workgroups (4/CU, all co-resident)
#define MAXNPW 256 // max dst nodes per workgroup (LDS sizing)
#define OVFCAP (1 << 20)   // overflow side-list capacity (1M recs, 16MB)
#define PBIN 16    // graph bins per pooling block (256 sorted nodes span <= ~4)

typedef unsigned int u32;
typedef u32 u2v __attribute__((ext_vector_type(2)));

__device__ __forceinline__ u32 pack_h2(float a, float b) {
    union { __half2 h; u32 u; } cv;
    cv.h = __floats2half2_rn(a, b);
    return cv.u;
}
__device__ __forceinline__ float2 unpack_h2(u32 u) {
    union { u32 u; __half2 h; } cv; cv.u = u;
    return __half22float2(cv.h);
}

// ---------------------------------------------------------------------------
// Per-node records. D (fp32, dst side, biases folded). S (fp16 packed).
// ---------------------------------------------------------------------------
__device__ __forceinline__ void compute_records_h(
    const float* __restrict__ hh,
    const float* __restrict__ fW, const float* __restrict__ fb,
    const float* __restrict__ sW, const float* __restrict__ sb,
    float* __restrict__ Dout, u32* __restrict__ Sout)
{
    float fsv[DH], ssv[DH];
#pragma unroll
    for (int j = 0; j < DH; ++j) {
        float fd = fb[j], sd = sb[j], fs = 0.f, ss = 0.f;
#pragma unroll
        for (int k = 0; k < DH; ++k) {
            fd += hh[k] * fW[j*23 + k];
            fs += hh[k] * fW[j*23 + 10 + k];
            sd += hh[k] * sW[j*23 + k];
            ss += hh[k] * sW[j*23 + 10 + k];
        }
        Dout[j]      = fd;
        Dout[DH + j] = sd;
        fsv[j] = fs;
        ssv[j] = ss;
    }
#pragma unroll
    for (int j = 0; j < 5; ++j) {
        Sout[j]     = pack_h2(fsv[2*j], fsv[2*j+1]);
        Sout[5 + j] = pack_h2(ssv[2*j], ssv[2*j+1]);
    }
}

// fp32 variant for the fallback path
__device__ __forceinline__ void compute_records(
    const float* __restrict__ hh,
    const float* __restrict__ fW, const float* __restrict__ fb,
    const float* __restrict__ sW, const float* __restrict__ sb,
    float* __restrict__ Dout, float* __restrict__ Sout)
{
#pragma unroll
    for (int j = 0; j < DH; ++j) {
        float fd = fb[j], sd = sb[j], fs = 0.f, ss = 0.f;
#pragma unroll
        for (int k = 0; k < DH; ++k) {
            fd += hh[k] * fW[j*23 + k];
            fs += hh[k] * fW[j*23 + 10 + k];
            sd += hh[k] * sW[j*23 + k];
            ss += hh[k] * sW[j*23 + 10 + k];
        }
        Dout[j]      = fd;
        Dout[DH + j] = sd;
        Sout[j]      = fs;
        Sout[DH + j] = ss;
    }
}

// ---------------------------------------------------------------------------
__global__ void zero_small(int* __restrict__ heads, int M, int* __restrict__ ovfh,
                           float* __restrict__ gsum, float* __restrict__ gcnt, int G)
{
    int i = blockIdx.x * blockDim.x + threadIdx.x;
    if (i < M) heads[i] = 0;
    if (i == 0) *ovfh = 0;
    if (i < G * DH) gsum[i] = 0.f;
    if (i < G) gcnt[i] = 0.f;
}

// ---------------------------------------------------------------------------
// P0: h0 = relu(x@preW.T+preb); layer-1 records
// ---------------------------------------------------------------------------
__global__ void node_pre_h(const float* __restrict__ x,
                           const float* __restrict__ preW, const float* __restrict__ preb,
                           const float* __restrict__ fW, const float* __restrict__ fb,
                           const float* __restrict__ sW, const float* __restrict__ sb,
                           float* __restrict__ h, float* __restrict__ D, u32* __restrict__ Sh,
                           int N)
{
    __shared__ float lpW[30], lpb[10], lfW[230], lfb[10], lsW[230], lsb[10];
    for (int i = threadIdx.x; i < 30;  i += blockDim.x) lpW[i] = preW[i];
    for (int i = threadIdx.x; i < 10;  i += blockDim.x) { lpb[i] = preb[i]; lfb[i] = fb[i]; lsb[i] = sb[i]; }
    for (int i = threadIdx.x; i < 230; i += blockDim.x) { lfW[i] = fW[i]; lsW[i] = sW[i]; }
    __syncthreads();

    int n = blockIdx.x * blockDim.x + threadIdx.x;
    if (n >= N) return;

    float x0 = x[(size_t)n*3], x1 = x[(size_t)n*3+1], x2 = x[(size_t)n*3+2];
    float hh[DH];
#pragma unroll
    for (int j = 0; j < DH; ++j)
        hh[j] = fmaxf(lpb[j] + x0*lpW[j*3] + x1*lpW[j*3+1] + x2*lpW[j*3+2], 0.f);

    float* hp = h + (size_t)n * DH;
#pragma unroll
    for (int j = 0; j < DH; ++j) hp[j] = hh[j];

    compute_records_h(hh, lfW, lfb, lsW, lsb, D + (size_t)n*REC, Sh + (size_t)n*SHU);
}

// ---------------------------------------------------------------------------
// One-pass scatter into capacity buckets keyed (slice, node).
// Edge rec 8B: w0 = src(18) | a2q(14)<<18 ; w1 = h2(a0,a1).
// csr stores are NONTEMPORAL (write-once stream; avoid L2 write-allocate thrash).
// ---------------------------------------------------------------------------
__global__ void scatter_cap(const int* __restrict__ ei, const float* __restrict__ attr,
                            int* __restrict__ heads, u32* __restrict__ csr,
                            uint4* __restrict__ ovf, int* __restrict__ ovfh,
                            int E, int N, int cap)
{
    int e = blockIdx.x * blockDim.x + threadIdx.x;
    if (e >= E) return;
    int src = __builtin_nontemporal_load(ei + e);
    int dst = __builtin_nontemporal_load(ei + (size_t)E + e);
    float a0 = __builtin_nontemporal_load(attr + (size_t)e * DE);
    float a1 = __builtin_nontemporal_load(attr + (size_t)e * DE + 1);
    float a2 = __builtin_nontemporal_load(attr + (size_t)e * DE + 2);
    int p = src >> SSH; if (p > NS - 1) p = NS - 1;
    u32 a2q = (u32)(fminf(fmaxf(a2, 0.f), 1.0f) * 16383.0f + 0.5f);
    u32 w0 = (u32)src | (a2q << 18);
    u32 w1 = pack_h2(a0, a1);

    size_t idx = (size_t)p * N + dst;
    int pos = atomicAdd(&heads[idx], 1);
    if (pos < cap) {
        u32* slot = csr + (idx * cap + pos) * 2;
        __builtin_nontemporal_store(w0, slot);
        __builtin_nontemporal_store(w1, slot + 1);
    } else {
        int op = atomicAdd(ovfh, 1);
        if (op < OVFCAP) ovf[op] = make_uint4((u32)dst, w0, w1, 0u);
    }
}

// ---------------------------------------------------------------------------
// Persistent gather: each wg owns npw dst nodes; drec+acc in LDS; walks src
// slices in lockstep (all wgs co-resident) -> slice S-records stay L2-resident.
// srec is 64B-aligned: exactly 3 same-line L2 transactions per record.
// ---------------------------------------------------------------------------
__global__ __launch_bounds__(256, 4) void gather_persist(
    const int* __restrict__ heads, const u32* __restrict__ csr, int cap,
    const float* __restrict__ D, const u32* __restrict__ ShU,
    const float* __restrict__ Wf, const float* __restrict__ Ws,
    float* __restrict__ accg, int N, int npw)
{
    __shared__ float s_drec[MAXNPW * REC];   // 20 KB
    __shared__ float s_acc[MAXNPW * DH];     // 10 KB

    int base = blockIdx.x * npw;
    if (base >= N) return;
    int cn = N - base; if (cn > npw) cn = npw;

    for (int i = threadIdx.x; i < cn * REC; i += 256)
        s_drec[i] = __builtin_nontemporal_load(D + (size_t)base * REC + i);
    for (int i = threadIdx.x; i < cn * DH; i += 256)
        s_acc[i] = 0.f;

    float wf[30], wsr[30];   // wave-uniform -> SGPRs
#pragma unroll
    for (int i = 0; i < 30; ++i) {
        int j = i / 3, t = i % 3;
        wf[i]  = Wf[j*23 + 20 + t];
        wsr[i] = Ws[j*23 + 20 + t];
    }
    __syncthreads();

    int g   = threadIdx.x >> 2;       // lane-group (node within chunk)
    int sub = threadIdx.x & (VEC - 1);
    int nchunk = (cn + 63) >> 6;

    for (int p = 0; p < NS; ++p) {
        for (int c = 0; c < nchunk; ++c) {
            int nl = (c << 6) + g;
            if (nl < cn) {
                size_t idx = (size_t)p * N + (base + nl);
                int cnt = heads[idx]; if (cnt > cap) cnt = cap;

                float partial[DH];
#pragma unroll
                for (int j = 0; j < DH; ++j) partial[j] = 0.f;

                if (cnt > 0) {
                    float dr[REC];
#pragma unroll
                    for (int j = 0; j < REC; ++j) dr[j] = s_drec[nl*REC + j];

                    size_t rb = idx * cap;
                    for (int q = sub; q < cnt; q += VEC) {
                        u2v c2 = __builtin_nontemporal_load(((const u2v*)csr) + rb + q);
                        u32 w0 = c2.x;
                        int src = (int)(w0 & 0x3FFFFu);
                        float a2 = (float)(w0 >> 18) * (1.0f / 16383.0f);
                        float2 a01 = unpack_h2(c2.y);
                        float a0 = a01.x, a1 = a01.y;

                        const uint4* sp = (const uint4*)(ShU + (size_t)src * SHU);
                        uint4 A = sp[0];
                        uint4 B = sp[1];
                        uint2 C = *(const uint2*)(sp + 2);
                        u32 u[10] = {A.x, A.y, A.z, A.w, B.x, B.y, B.z, B.w, C.x, C.y};
                        float s[20];
#pragma unroll
                        for (int i = 0; i < 10; ++i) {
                            float2 f = unpack_h2(u[i]);
                            s[2*i] = f.x; s[2*i+1] = f.y;
                        }
#pragma unroll
                        for (int j = 0; j < DH; ++j) {
                            float pf = dr[j]      + s[j]      + a0*wf[j*3]  + a1*wf[j*3+1]  + a2*wf[j*3+2];
                            float ps = dr[DH + j] + s[DH + j] + a0*wsr[j*3] + a1*wsr[j*3+1] + a2*wsr[j*3+2];
                            float sg  = __builtin_amdgcn_rcpf(1.0f + __expf(-pf));           // sigmoid
                            float sp2 = fmaxf(ps, 0.f) + __logf(1.0f + __expf(-fabsf(ps)));  // softplus
                            partial[j] += sg * sp2;
                        }
                    }
                }
#pragma unroll
                for (int j = 0; j < DH; ++j) {
                    partial[j] += __shfl_xor(partial[j], 1);
                    partial[j] += __shfl_xor(partial[j], 2);
                }
                if (sub == 0 && cnt > 0) {
#pragma unroll
                    for (int j = 0; j < DH; ++j) s_acc[nl*DH + j] += partial[j];
                }
            }
        }
        __syncthreads();   // keep the wg's waves slice-aligned
    }

    for (int i = threadIdx.x; i < cn * DH; i += 256)
        accg[(size_t)base * DH + i] = s_acc[i];
}

// ---------------------------------------------------------------------------
// Overflow pass (runs after gather_persist): ~1e4 edges, global atomics.
// ---------------------------------------------------------------------------
__global__ void ovf_pass(const uint4* __restrict__ ovf, const int* __restrict__ ovfh,
                         const float* __restrict__ D, const u32* __restrict__ ShU,
                         const float* __restrict__ Wf, const float* __restrict__ Ws,
                         float* __restrict__ accg)
{
    __shared__ float wf[30], wsr[30];
    if (threadIdx.x < 30) {
        int j = threadIdx.x / 3, t = threadIdx.x % 3;
        wf[threadIdx.x]  = Wf[j*23 + 20 + t];
        wsr[threadIdx.x] = Ws[j*23 + 20 + t];
    }
    __syncthreads();

    int oc = *ovfh; if (oc > OVFCAP) oc = OVFCAP;
    for (int i = blockIdx.x * blockDim.x + threadIdx.x; i < oc;
         i += gridDim.x * blockDim.x) {
        uint4 e = ovf[i];
        int dst = (int)e.x;
        u32 w0 = e.y;
        int src = (int)(w0 & 0x3FFFFu);
        float a2 = (float)(w0 >> 18) * (1.0f / 16383.0f);
        float2 a01 = unpack_h2(e.z);
        float a0 = a01.x, a1 = a01.y;

        float dr[REC];
        const float4* dp = (const float4*)(D + (size_t)dst * REC);
#pragma unroll
        for (int k = 0; k < 5; ++k) ((float4*)dr)[k] = dp[k];

        const uint4* sp = (const uint4*)(ShU + (size_t)src * SHU);
        uint4 A = sp[0];
        uint4 B = sp[1];
        uint2 C = *(const uint2*)(sp + 2);
        u32 u[10] = {A.x, A.y, A.z, A.w, B.x, B.y, B.z, B.w, C.x, C.y};
        float s[20];
#pragma unroll
        for (int k = 0; k < 10; ++k) {
            float2 f = unpack_h2(u[k]);
            s[2*k] = f.x; s[2*k+1] = f.y;
        }
        float* ap = accg + (size_t)dst * DH;
#pragma unroll
        for (int j = 0; j < DH; ++j) {
            float pf = dr[j]      + s[j]      + a0*wf[j*3]  + a1*wf[j*3+1]  + a2*wf[j*3+2];
            float ps = dr[DH + j] + s[DH + j] + a0*wsr[j*3] + a1*wsr[j*3+1] + a2*wsr[j*3+2];
            float sg  = __builtin_amdgcn_rcpf(1.0f + __expf(-pf));
            float sp2 = fmaxf(ps, 0.f) + __logf(1.0f + __expf(-fabsf(ps)));
            atomicAdd(ap + j, sg * sp2);
        }
    }
}

// ---------------------------------------------------------------------------
// Layer-1 epilogue: h = relu(h + acc); records for layer 2
// ---------------------------------------------------------------------------
__global__ void node_mid_h(float* __restrict__ h, const float* __restrict__ acc,
                           const float* __restrict__ fW, const float* __restrict__ fb,
                           const float* __restrict__ sW, const float* __restrict__ sb,
                           float* __restrict__ D, u32* __restrict__ Sh, int N)
{
    __shared__ float lfW[230], lfb[10], lsW[230], lsb[10];
    for (int i = threadIdx.x; i < 230; i += blockDim.x) { lfW[i] = fW[i]; lsW[i] = sW[i]; }
    for (int i = threadIdx.x; i < 10;  i += blockDim.x) { lfb[i] = fb[i]; lsb[i] = sb[i]; }
    __syncthreads();
    int n = blockIdx.x * blockDim.x + threadIdx.x;
    if (n >= N) return;
    float* hp = h + (size_t)n * DH;
    const float* ap = acc + (size_t)n * DH;
    float hh[DH];
#pragma unroll
    for (int j = 0; j < DH; ++j) {
        hh[j] = fmaxf(hp[j] + ap[j], 0.f);
        hp[j] = hh[j];
    }
    compute_records_h(hh, lfW, lfb, lsW, lsb, D + (size_t)n*REC, Sh + (size_t)n*SHU);
}

// ---------------------------------------------------------------------------
// Layer-2 epilogue + pooling: segmented block-local reduction (batch sorted).
// ---------------------------------------------------------------------------
__global__ void node_pool(const float* __restrict__ h, const float* __restrict__ acc,
                          const int* __restrict__ batch,
                          float* __restrict__ gsum, float* __restrict__ gcnt, int N)
{
    __shared__ float lg[PBIN * DH];
    __shared__ float lc[PBIN];

    int base = blockIdx.x * blockDim.x;
    int n = base + threadIdx.x;

    for (int i = threadIdx.x; i < PBIN * DH; i += blockDim.x) lg[i] = 0.f;
    if (threadIdx.x < PBIN) lc[threadIdx.x] = 0.f;
    __syncthreads();

    int b0 = batch[base];   // uniform across block (sorted)

    if (n < N) {
        int b = batch[n];
        int off = b - b0;
        const float* hp = h + (size_t)n * DH;
        const float* ap = acc + (size_t)n * DH;
        float v[DH];
#pragma unroll
        for (int j = 0; j < DH; ++j) v[j] = fmaxf(hp[j] + ap[j], 0.f);

        if (off < PBIN) {
#pragma unroll
            for (int j = 0; j < DH; ++j) atomicAdd(&lg[off * DH + j], v[j]);
            atomicAdd(&lc[off], 1.f);
        } else {   // statistically impossible (256 sorted nodes span ~4 graphs)
            float* gp = gsum + (size_t)b * DH;
#pragma unroll
            for (int j = 0; j < DH; ++j) atomicAdd(gp + j, v[j]);
            atomicAdd(gcnt + b, 1.f);
        }
    }
    __syncthreads();

    for (int i = threadIdx.x; i < PBIN * DH; i += blockDim.x) {
        int g = i / DH;
        if (lc[g] > 0.f)
            atomicAdd(&gsum[(size_t)(b0 + g) * DH + (i - g * DH)], lg[i]);
    }
    if (threadIdx.x < PBIN && lc[threadIdx.x] > 0.f)
        atomicAdd(&gcnt[b0 + threadIdx.x], lc[threadIdx.x]);
}

// ---------------------------------------------------------------------------
// Fallback path kernels (fp32 atomic path; used only if ws too small / N too big)
// ---------------------------------------------------------------------------
__global__ void node_pre_f32(const float* __restrict__ x,
                             const float* __restrict__ preW, const float* __restrict__ preb,
                             const float* __restrict__ fW, const float* __restrict__ fb,
                             const float* __restrict__ sW, const float* __restrict__ sb,
                             float* __restrict__ h, float* __restrict__ D, float* __restrict__ S,
                             float* __restrict__ agg,
                             float* __restrict__ gsum, float* __restrict__ gcnt, int N, int G)
{
    __shared__ float lpW[30], lpb[10], lfW[230], lfb[10], lsW[230], lsb[10];
    for (int i = threadIdx.x; i < 30;  i += blockDim.x) lpW[i] = preW[i];
    for (int i = threadIdx.x; i < 10;  i += blockDim.x) { lpb[i] = preb[i]; lfb[i] = fb[i]; lsb[i] = sb[i]; }
    for (int i = threadIdx.x; i < 230; i += blockDim.x) { lfW[i] = fW[i]; lsW[i] = sW[i]; }
    __syncthreads();
    int n = blockIdx.x * blockDim.x + threadIdx.x;
    if (n < G * DH) gsum[n] = 0.f;
    if (n < G)      gcnt[n] = 0.f;
    if (n >= N) return;
    float x0 = x[(size_t)n*3], x1 = x[(size_t)n*3+1], x2 = x[(size_t)n*3+2];
    float hh[DH];
#pragma unroll
    for (int j = 0; j < DH; ++j)
        hh[j] = fmaxf(lpb[j] + x0*lpW[j*3] + x1*lpW[j*3+1] + x2*lpW[j*3+2], 0.f);
    float* hp = h + (size_t)n * DH;
    float* ap = agg + (size_t)n * DH;
#pragma unroll
    for (int j = 0; j < DH; ++j) { hp[j] = hh[j]; ap[j] = 0.f; }
    compute_records(hh, lfW, lfb, lsW, lsb, D + (size_t)n*REC, S + (size_t)n*REC);
}

__global__ void edge_pass(const int* __restrict__ ei, const float* __restrict__ attr,
                          const float* __restrict__ D, const float* __restrict__ S,
                          const float* __restrict__ Wf, const float* __restrict__ Ws,
                          float* __restrict__ agg, int E)
{
    __shared__ float wfe[30], wse[30];
    if (threadIdx.x < 30) {
        int j = threadIdx.x / 3, t = threadIdx.x % 3;
        wfe[threadIdx.x] = Wf[j*23 + 20 + t];
        wse[threadIdx.x] = Ws[j*23 + 20 + t];
    }
    __syncthreads();
    int e = blockIdx.x * blockDim.x + threadIdx.x;
    if (e >= E) return;
    int src = ei[e];
    int dst = ei[(size_t)E + e];
    const float* eap = attr + (size_t)e * DE;
    float ea0 = eap[0], ea1 = eap[1], ea2 = eap[2];
    float drec[REC], srec[REC];
    const float4* Dp = (const float4*)(D + (size_t)dst * REC);
    const float4* Sp = (const float4*)(S + (size_t)src * REC);
#pragma unroll
    for (int i = 0; i < 5; ++i) { ((float4*)drec)[i] = Dp[i]; ((float4*)srec)[i] = Sp[i]; }
    float* ap = agg + (size_t)dst * DH;
#pragma unroll
    for (int j = 0; j < DH; ++j) {
        float pf = drec[j]      + srec[j]      + ea0*wfe[j*3] + ea1*wfe[j*3+1] + ea2*wfe[j*3+2];
        float ps = drec[DH + j] + srec[DH + j] + ea0*wse[j*3] + ea1*wse[j*3+1] + ea2*wse[j*3+2];
        float sg = 1.0f / (1.0f + __expf(-pf));
        float sp = fmaxf(ps, 0.f) + log1pf(__expf(-fabsf(ps)));
        atomicAdd(ap + j, sg * sp);
    }
}

__global__ void node_mid(float* __restrict__ h, float* __restrict__ agg,
                         const float* __restrict__ fW, const float* __restrict__ fb,
                         const float* __restrict__ sW, const float* __restrict__ sb,
                         float* __restrict__ D, float* __restrict__ S, int N)
{
    __shared__ float lfW[230], lfb[10], lsW[230], lsb[10];
    for (int i = threadIdx.x; i < 230; i += blockDim.x) { lfW[i] = fW[i]; lsW[i] = sW[i]; }
    for (int i = threadIdx.x; i < 10;  i += blockDim.x) { lfb[i] = fb[i]; lsb[i] = sb[i]; }
    __syncthreads();
    int n = blockIdx.x * blockDim.x + threadIdx.x;
    if (n >= N) return;
    float* hp = h + (size_t)n * DH;
    float* ap = agg + (size_t)n * DH;
    float hh[DH];
#pragma unroll
    for (int j = 0; j < DH; ++j) {
        hh[j] = fmaxf(hp[j] + ap[j], 0.f);
        hp[j] = hh[j];
        ap[j] = 0.f;
    }
    compute_records(hh, lfW, lfb, lsW, lsb, D + (size_t)n*REC, S + (size_t)n*REC);
}

__global__ void node_post(const float* __restrict__ h, const float* __restrict__ agg,
                          const int* __restrict__ batch,
                          float* __restrict__ gsum, float* __restrict__ gcnt, int N)
{
    int n = blockIdx.x * blockDim.x + threadIdx.x;
    if (n >= N) return;
    int b = batch[n];
    const float* hp = h + (size_t)n * DH;
    const float* ap = agg + (size_t)n * DH;
    float* gp = gsum + (size_t)b * DH;
#pragma unroll
    for (int j = 0; j < DH; ++j)
        atomicAdd(gp + j, fmaxf(hp[j] + ap[j], 0.f));
    atomicAdd(gcnt + b, 1.f);
}

// ---------------------------------------------------------------------------
// MLP head: one block (128 threads) per graph.
// ---------------------------------------------------------------------------
__global__ void mlp_head(const float* __restrict__ gsum, const float* __restrict__ gcnt,
                         const float* __restrict__ fc1W, const float* __restrict__ fc1b,
                         const float* __restrict__ fc2W, const float* __restrict__ fc2b,
                         const float* __restrict__ outW, const float* __restrict__ outb,
                         float* __restrict__ out, int G)
{
    __shared__ float g[DH], a1[128], a2[128];
    int gid = blockIdx.x;
    int t = threadIdx.x;
    if (t < DH) {
        float c = fmaxf(gcnt[gid], 1.0f);
        g[t] = gsum[(size_t)gid*DH + t] / c;
    }
    __syncthreads();
    {
        float acc = fc1b[t];
        const float* w = fc1W + (size_t)t * DH;
#pragma unroll
        for (int k = 0; k < DH; ++k) acc += w[k] * g[k];
        a1[t] = fmaxf(acc, 0.f);
    }
    __syncthreads();
    {
        float acc = fc2b[t];
        const float* w = fc2W + (size_t)t * 128;
#pragma unroll 8
        for (int k = 0; k < 128; ++k) acc += w[k] * a1[k];
        a2[t] = fmaxf(acc, 0.f);
    }
    __syncthreads();
    if (t < 3) {
        float acc = outb[t];
        const float* w = outW + (size_t)t * 128;
#pragma unroll 8
        for (int k = 0; k < 128; ++k) acc += w[k] * a2[k];
        out[(size_t)gid*3 + t] = acc;
    }
}

// ---------------------------------------------------------------------------
extern "C" void kernel_launch(void* const* d_in, const int* in_sizes, int n_in,
                              void* d_out, int out_size, void* d_ws, size_t ws_size,
                              hipStream_t stream)
{
    const float* x     = (const float*)d_in[0];
    const int*   ei    = (const int*)  d_in[1];
    const float* attr  = (const float*)d_in[2];
    const int*   batch = (const int*)  d_in[3];
    const float* preW  = (const float*)d_in[4];
    const float* preb  = (const float*)d_in[5];
    const float* f1W   = (const float*)d_in[6];
    const float* f1b   = (const float*)d_in[7];
    const float* s1W   = (const float*)d_in[8];
    const float* s1b   = (const float*)d_in[9];
    const float* f2W   = (const float*)d_in[10];
    const float* f2b   = (const float*)d_in[11];
    const float* s2W   = (const float*)d_in[12];
    const float* s2b   = (const float*)d_in[13];
    const float* fc1W  = (const float*)d_in[14];
    const float* fc1b  = (const float*)d_in[15];
    const float* fc2W  = (const float*)d_in[16];
    const float* fc2b  = (const float*)d_in[17];
    const float* outW  = (const float*)d_in[18];
    const float* outb  = (const float*)d_in[19];

    const int N = in_sizes[0] / DIN;          // 200000
    const int E = in_sizes[1] / 2;            // 6400000
    const int G = out_size / 3;               // 1024
    const int M = NS * N;                     // bucket-head table size
    const int npw = (N + WGN - 1) / WGN;      // 196 dst nodes per persistent wg

    const int TB = 256;
    const int nb = (N + TB - 1) / TB;
    const int eb = (E + TB - 1) / TB;
    const int zb = ((M > G * DH ? M : G * DH) + TB - 1) / TB;

    // ---- workspace layout (csr capacity computed from remaining budget) ----
    size_t f_off = 0;
    float* ws = (float*)d_ws;
    float* h    = ws + f_off; f_off += (size_t)N * DH;
    float* D    = ws + f_off; f_off += (size_t)N * REC;
    f_off = (f_off + 15) & ~(size_t)15;                        // 64B-align Sh
    u32*   Sh   = (u32*)(ws + f_off); f_off += (size_t)N * SHU;
    float* acc  = ws + f_off; f_off += (size_t)N * DH;
    float* gsum = ws + f_off; f_off += (size_t)G * DH;
    float* gcnt = ws + f_off; f_off += G;
    f_off = (f_off + 15) & ~(size_t)15;
    int* heads  = (int*)(ws + f_off); f_off += M;
    int* ovfh   = (int*)(ws + f_off); f_off += 1;
    f_off = (f_off + 15) & ~(size_t)15;
    uint4* ovf  = (uint4*)(ws + f_off); f_off += (size_t)OVFCAP * 4;
    f_off = (f_off + 15) & ~(size_t)15;
    u32* csr    = (u32*)(ws + f_off);

    size_t core_bytes = f_off * sizeof(float);
    long long budget = (long long)ws_size - (long long)core_bytes;
    int cap = 0;
    if (budget > 0) cap = (int)(budget / ((long long)M * 8));
    if (cap > 16) cap = 16;

    if (cap >= 6 && npw <= MAXNPW && N < (1 << 18)) {
        // ===== capacity-bucket + persistent slice-walk path =====
        zero_small<<<zb, TB, 0, stream>>>(heads, M, ovfh, gsum, gcnt, G);
        node_pre_h<<<nb, TB, 0, stream>>>(x, preW, preb, f1W, f1b, s1W, s1b,
                                          h, D, Sh, N);
        scatter_cap<<<eb, TB, 0, stream>>>(ei, attr, heads, csr, ovf, ovfh, E, N, cap);

        gather_persist<<<WGN, 256, 0, stream>>>(heads, csr, cap, D, Sh,
                                                f1W, s1W, acc, N, npw);
        ovf_pass<<<256, 256, 0, stream>>>(ovf, ovfh, D, Sh, f1W, s1W, acc);
        node_mid_h<<<nb, TB, 0, stream>>>(h, acc, f2W, f2b, s2W, s2b, D, Sh, N);

        gather_persist<<<WGN, 256, 0, stream>>>(heads, csr, cap, D, Sh,
                                                f2W, s2W, acc, N, npw);
        ovf_pass<<<256, 256, 0, stream>>>(ovf, ovfh, D, Sh, f2W, s2W, acc);
        node_pool<<<nb, TB, 0, stream>>>(h, acc, batch, gsum, gcnt, N);
        mlp_head<<<G, 128, 0, stream>>>(gsum, gcnt, fc1W, fc1b, fc2W, fc2b,
                                        outW, outb, (float*)d_out, G);
    } else {
        // ===== fallback: fp32 atomic path =====
        size_t o = 0;
        float* fh    = ws + o; o += (size_t)N * DH;
        float* agg   = ws + o; o += (size_t)N * DH;
        float* fD    = ws + o; o += (size_t)N * REC;
        float* fS    = ws + o; o += (size_t)N * REC;
        float* fgsum = ws + o; o += (size_t)G * DH;
        float* fgcnt = ws + o; o += G;

        node_pre_f32<<<nb, TB, 0, stream>>>(x, preW, preb, f1W, f1b, s1W, s1b,
                                            fh, fD, fS, agg, fgsum, fgcnt, N, G);
        edge_pass<<<eb, TB, 0, stream>>>(ei, attr, fD, fS, f1W, s1W, agg, E);
        node_mid<<<nb, TB, 0, stream>>>(fh, agg, f2W, f2b, s2W, s2b, fD, fS, N);
        edge_pass<<<eb, TB, 0, stream>>>(ei, attr, fD, fS, f2W, s2W, agg, E);
        node_post<<<nb, TB, 0, stream>>>(fh, agg, batch, fgsum, fgcnt, N);
        mlp_head<<<G, 128, 0, stream>>>(fgsum, fgcnt, fc1W, fc1b, fc2W, fc2b,
                                        outW, outb, (float*)d_out, G);
    }
}

// Round 14
// 934.688 us; speedup vs baseline: 1.1773x; 1.1773x over previous
//
#include <hip/hip_runtime.h>
#include <hip/hip_bf16.h>
#include <hip/hip_fp16.h>
#include <math.h>

#define DH 10      // hidden dim
#define DE 3       // edge attr dim
#define DIN 3      // input dim
#define REC 20     // fp32 D record: 20 floats = 80B
#define SHU 16     // fp16 S record stride in uints: 64B-ALIGNED (10 used) -> 1 line/record
#define VEC 4      // lanes cooperating per node in gather
#define SSH 15     // slice shift
#define NS 6       // slices 0..5 (slice 5 merged tail); slice = 32768*64B = 2MB (L2-resident)
#define WGN 1280   // persistent workgroups (5/CU x 256 CUs, all co-resident; LDS 30KB*5=150KB)
#define MAXNPW 256 // max dst nodes per workgroup (LDS sizing)
#define OVFCAP (1 << 20)   // overflow side-list capacity (1M recs, 16MB)
#define PBIN 16    // graph bins per pooling block (256 sorted nodes span <= ~4)

typedef unsigned int u32;
typedef u32 u2v __attribute__((ext_vector_type(2)));

__device__ __forceinline__ u32 pack_h2(float a, float b) {
    union { __half2 h; u32 u; } cv;
    cv.h = __floats2half2_rn(a, b);
    return cv.u;
}
__device__ __forceinline__ float2 unpack_h2(u32 u) {
    union { u32 u; __half2 h; } cv; cv.u = u;
    return __half22float2(cv.h);
}

// ---------------------------------------------------------------------------
// Per-node records. D (fp32, dst side, biases folded). S (fp16 packed).
// ---------------------------------------------------------------------------
__device__ __forceinline__ void compute_records_h(
    const float* __restrict__ hh,
    const float* __restrict__ fW, const float* __restrict__ fb,
    const float* __restrict__ sW, const float* __restrict__ sb,
    float* __restrict__ Dout, u32* __restrict__ Sout)
{
    float fsv[DH], ssv[DH];
#pragma unroll
    for (int j = 0; j < DH; ++j) {
        float fd = fb[j], sd = sb[j], fs = 0.f, ss = 0.f;
#pragma unroll
        for (int k = 0; k < DH; ++k) {
            fd += hh[k] * fW[j*23 + k];
            fs += hh[k] * fW[j*23 + 10 + k];
            sd += hh[k] * sW[j*23 + k];
            ss += hh[k] * sW[j*23 + 10 + k];
        }
        Dout[j]      = fd;
        Dout[DH + j] = sd;
        fsv[j] = fs;
        ssv[j] = ss;
    }
#pragma unroll
    for (int j = 0; j < 5; ++j) {
        Sout[j]     = pack_h2(fsv[2*j], fsv[2*j+1]);
        Sout[5 + j] = pack_h2(ssv[2*j], ssv[2*j+1]);
    }
}

// fp32 variant for the fallback path
__device__ __forceinline__ void compute_records(
    const float* __restrict__ hh,
    const float* __restrict__ fW, const float* __restrict__ fb,
    const float* __restrict__ sW, const float* __restrict__ sb,
    float* __restrict__ Dout, float* __restrict__ Sout)
{
#pragma unroll
    for (int j = 0; j < DH; ++j) {
        float fd = fb[j], sd = sb[j], fs = 0.f, ss = 0.f;
#pragma unroll
        for (int k = 0; k < DH; ++k) {
            fd += hh[k] * fW[j*23 + k];
            fs += hh[k] * fW[j*23 + 10 + k];
            sd += hh[k] * sW[j*23 + k];
            ss += hh[k] * sW[j*23 + 10 + k];
        }
        Dout[j]      = fd;
        Dout[DH + j] = sd;
        Sout[j]      = fs;
        Sout[DH + j] = ss;
    }
}

// ---------------------------------------------------------------------------
__global__ void zero_small(int* __restrict__ heads, int M, int* __restrict__ ovfh,
                           float* __restrict__ gsum, float* __restrict__ gcnt, int G)
{
    int i = blockIdx.x * blockDim.x + threadIdx.x;
    if (i < M) heads[i] = 0;
    if (i == 0) *ovfh = 0;
    if (i < G * DH) gsum[i] = 0.f;
    if (i < G) gcnt[i] = 0.f;
}

// ---------------------------------------------------------------------------
// P0: h0 = relu(x@preW.T+preb); layer-1 records
// ---------------------------------------------------------------------------
__global__ void node_pre_h(const float* __restrict__ x,
                           const float* __restrict__ preW, const float* __restrict__ preb,
                           const float* __restrict__ fW, const float* __restrict__ fb,
                           const float* __restrict__ sW, const float* __restrict__ sb,
                           float* __restrict__ h, float* __restrict__ D, u32* __restrict__ Sh,
                           int N)
{
    __shared__ float lpW[30], lpb[10], lfW[230], lfb[10], lsW[230], lsb[10];
    for (int i = threadIdx.x; i < 30;  i += blockDim.x) lpW[i] = preW[i];
    for (int i = threadIdx.x; i < 10;  i += blockDim.x) { lpb[i] = preb[i]; lfb[i] = fb[i]; lsb[i] = sb[i]; }
    for (int i = threadIdx.x; i < 230; i += blockDim.x) { lfW[i] = fW[i]; lsW[i] = sW[i]; }
    __syncthreads();

    int n = blockIdx.x * blockDim.x + threadIdx.x;
    if (n >= N) return;

    float x0 = x[(size_t)n*3], x1 = x[(size_t)n*3+1], x2 = x[(size_t)n*3+2];
    float hh[DH];
#pragma unroll
    for (int j = 0; j < DH; ++j)
        hh[j] = fmaxf(lpb[j] + x0*lpW[j*3] + x1*lpW[j*3+1] + x2*lpW[j*3+2], 0.f);

    float* hp = h + (size_t)n * DH;
#pragma unroll
    for (int j = 0; j < DH; ++j) hp[j] = hh[j];

    compute_records_h(hh, lfW, lfb, lsW, lsb, D + (size_t)n*REC, Sh + (size_t)n*SHU);
}

// ---------------------------------------------------------------------------
// One-pass scatter into capacity buckets keyed (slice, node).
// Edge rec 8B: w0 = src(18) | a2q(14)<<18 ; w1 = h2(a0,a1). Single uint2 store
// (R12 known-good form; nt split-store experiment regressed - reverted).
// ---------------------------------------------------------------------------
__global__ void scatter_cap(const int* __restrict__ ei, const float* __restrict__ attr,
                            int* __restrict__ heads, uint2* __restrict__ csr,
                            uint4* __restrict__ ovf, int* __restrict__ ovfh,
                            int E, int N, int cap)
{
    int e = blockIdx.x * blockDim.x + threadIdx.x;
    if (e >= E) return;
    int src = __builtin_nontemporal_load(ei + e);
    int dst = __builtin_nontemporal_load(ei + (size_t)E + e);
    float a0 = __builtin_nontemporal_load(attr + (size_t)e * DE);
    float a1 = __builtin_nontemporal_load(attr + (size_t)e * DE + 1);
    float a2 = __builtin_nontemporal_load(attr + (size_t)e * DE + 2);
    int p = src >> SSH; if (p > NS - 1) p = NS - 1;
    u32 a2q = (u32)(fminf(fmaxf(a2, 0.f), 1.0f) * 16383.0f + 0.5f);
    u32 w0 = (u32)src | (a2q << 18);
    u32 w1 = pack_h2(a0, a1);

    size_t idx = (size_t)p * N + dst;
    int pos = atomicAdd(&heads[idx], 1);
    if (pos < cap) {
        csr[idx * cap + pos] = make_uint2(w0, w1);
    } else {
        int op = atomicAdd(ovfh, 1);
        if (op < OVFCAP) ovf[op] = make_uint4((u32)dst, w0, w1, 0u);
    }
}

// ---------------------------------------------------------------------------
// Persistent gather: each wg owns npw dst nodes; drec+acc in LDS; walks src
// slices in lockstep (all wgs co-resident) -> slice S-records stay L2-resident.
// 5 blocks/CU (20 waves) for miss-concurrency; srec 64B-aligned (1 line/rec).
// ---------------------------------------------------------------------------
__global__ __launch_bounds__(256, 5) void gather_persist(
    const int* __restrict__ heads, const uint2* __restrict__ csr, int cap,
    const float* __restrict__ D, const u32* __restrict__ ShU,
    const float* __restrict__ Wf, const float* __restrict__ Ws,
    float* __restrict__ accg, int N, int npw)
{
    __shared__ float s_drec[MAXNPW * REC];   // 20 KB
    __shared__ float s_acc[MAXNPW * DH];     // 10 KB

    int base = blockIdx.x * npw;
    if (base >= N) return;
    int cn = N - base; if (cn > npw) cn = npw;

    for (int i = threadIdx.x; i < cn * REC; i += 256)
        s_drec[i] = __builtin_nontemporal_load(D + (size_t)base * REC + i);
    for (int i = threadIdx.x; i < cn * DH; i += 256)
        s_acc[i] = 0.f;

    float wf[30], wsr[30];   // wave-uniform -> SGPRs
#pragma unroll
    for (int i = 0; i < 30; ++i) {
        int j = i / 3, t = i % 3;
        wf[i]  = Wf[j*23 + 20 + t];
        wsr[i] = Ws[j*23 + 20 + t];
    }
    __syncthreads();

    int g   = threadIdx.x >> 2;       // lane-group (node within chunk)
    int sub = threadIdx.x & (VEC - 1);
    int nchunk = (cn + 63) >> 6;

    for (int p = 0; p < NS; ++p) {
        for (int c = 0; c < nchunk; ++c) {
            int nl = (c << 6) + g;
            if (nl < cn) {
                size_t idx = (size_t)p * N + (base + nl);
                int cnt = heads[idx]; if (cnt > cap) cnt = cap;

                float partial[DH];
#pragma unroll
                for (int j = 0; j < DH; ++j) partial[j] = 0.f;

                if (cnt > 0) {
                    float dr[REC];
#pragma unroll
                    for (int j = 0; j < REC; ++j) dr[j] = s_drec[nl*REC + j];

                    size_t rb = idx * cap;
                    for (int q = sub; q < cnt; q += VEC) {
                        u2v c2 = __builtin_nontemporal_load(((const u2v*)csr) + rb + q);
                        u32 w0 = c2.x;
                        int src = (int)(w0 & 0x3FFFFu);
                        float a2 = (float)(w0 >> 18) * (1.0f / 16383.0f);
                        float2 a01 = unpack_h2(c2.y);
                        float a0 = a01.x, a1 = a01.y;

                        const uint4* sp = (const uint4*)(ShU + (size_t)src * SHU);
                        uint4 A = sp[0];
                        uint4 B = sp[1];
                        uint2 C = *(const uint2*)(sp + 2);
                        u32 u[10] = {A.x, A.y, A.z, A.w, B.x, B.y, B.z, B.w, C.x, C.y};
                        float s[20];
#pragma unroll
                        for (int i = 0; i < 10; ++i) {
                            float2 f = unpack_h2(u[i]);
                            s[2*i] = f.x; s[2*i+1] = f.y;
                        }
#pragma unroll
                        for (int j = 0; j < DH; ++j) {
                            float pf = dr[j]      + s[j]      + a0*wf[j*3]  + a1*wf[j*3+1]  + a2*wf[j*3+2];
                            float ps = dr[DH + j] + s[DH + j] + a0*wsr[j*3] + a1*wsr[j*3+1] + a2*wsr[j*3+2];
                            float sg  = __builtin_amdgcn_rcpf(1.0f + __expf(-pf));           // sigmoid
                            float sp2 = fmaxf(ps, 0.f) + __logf(1.0f + __expf(-fabsf(ps)));  // softplus
                            partial[j] += sg * sp2;
                        }
                    }
                }
#pragma unroll
                for (int j = 0; j < DH; ++j) {
                    partial[j] += __shfl_xor(partial[j], 1);
                    partial[j] += __shfl_xor(partial[j], 2);
                }
                if (sub == 0 && cnt > 0) {
#pragma unroll
                    for (int j = 0; j < DH; ++j) s_acc[nl*DH + j] += partial[j];
                }
            }
        }
        __syncthreads();   // keep the wg's waves slice-aligned
    }

    for (int i = threadIdx.x; i < cn * DH; i += 256)
        accg[(size_t)base * DH + i] = s_acc[i];
}

// ---------------------------------------------------------------------------
// Overflow pass (runs after gather_persist): ~1e4 edges, global atomics.
// ---------------------------------------------------------------------------
__global__ void ovf_pass(const uint4* __restrict__ ovf, const int* __restrict__ ovfh,
                         const float* __restrict__ D, const u32* __restrict__ ShU,
                         const float* __restrict__ Wf, const float* __restrict__ Ws,
                         float* __restrict__ accg)
{
    __shared__ float wf[30], wsr[30];
    if (threadIdx.x < 30) {
        int j = threadIdx.x / 3, t = threadIdx.x % 3;
        wf[threadIdx.x]  = Wf[j*23 + 20 + t];
        wsr[threadIdx.x] = Ws[j*23 + 20 + t];
    }
    __syncthreads();

    int oc = *ovfh; if (oc > OVFCAP) oc = OVFCAP;
    for (int i = blockIdx.x * blockDim.x + threadIdx.x; i < oc;
         i += gridDim.x * blockDim.x) {
        uint4 e = ovf[i];
        int dst = (int)e.x;
        u32 w0 = e.y;
        int src = (int)(w0 & 0x3FFFFu);
        float a2 = (float)(w0 >> 18) * (1.0f / 16383.0f);
        float2 a01 = unpack_h2(e.z);
        float a0 = a01.x, a1 = a01.y;

        float dr[REC];
        const float4* dp = (const float4*)(D + (size_t)dst * REC);
#pragma unroll
        for (int k = 0; k < 5; ++k) ((float4*)dr)[k] = dp[k];

        const uint4* sp = (const uint4*)(ShU + (size_t)src * SHU);
        uint4 A = sp[0];
        uint4 B = sp[1];
        uint2 C = *(const uint2*)(sp + 2);
        u32 u[10] = {A.x, A.y, A.z, A.w, B.x, B.y, B.z, B.w, C.x, C.y};
        float s[20];
#pragma unroll
        for (int k = 0; k < 10; ++k) {
            float2 f = unpack_h2(u[k]);
            s[2*k] = f.x; s[2*k+1] = f.y;
        }
        float* ap = accg + (size_t)dst * DH;
#pragma unroll
        for (int j = 0; j < DH; ++j) {
            float pf = dr[j]      + s[j]      + a0*wf[j*3]  + a1*wf[j*3+1]  + a2*wf[j*3+2];
            float ps = dr[DH + j] + s[DH + j] + a0*wsr[j*3] + a1*wsr[j*3+1] + a2*wsr[j*3+2];
            float sg  = __builtin_amdgcn_rcpf(1.0f + __expf(-pf));
            float sp2 = fmaxf(ps, 0.f) + __logf(1.0f + __expf(-fabsf(ps)));
            atomicAdd(ap + j, sg * sp2);
        }
    }
}

// ---------------------------------------------------------------------------
// Layer-1 epilogue: h = relu(h + acc); records for layer 2
// ---------------------------------------------------------------------------
__global__ void node_mid_h(float* __restrict__ h, const float* __restrict__ acc,
                           const float* __restrict__ fW, const float* __restrict__ fb,
                           const float* __restrict__ sW, const float* __restrict__ sb,
                           float* __restrict__ D, u32* __restrict__ Sh, int N)
{
    __shared__ float lfW[230], lfb[10], lsW[230], lsb[10];
    for (int i = threadIdx.x; i < 230; i += blockDim.x) { lfW[i] = fW[i]; lsW[i] = sW[i]; }
    for (int i = threadIdx.x; i < 10;  i += blockDim.x) { lfb[i] = fb[i]; lsb[i] = sb[i]; }
    __syncthreads();
    int n = blockIdx.x * blockDim.x + threadIdx.x;
    if (n >= N) return;
    float* hp = h + (size_t)n * DH;
    const float* ap = acc + (size_t)n * DH;
    float hh[DH];
#pragma unroll
    for (int j = 0; j < DH; ++j) {
        hh[j] = fmaxf(hp[j] + ap[j], 0.f);
        hp[j] = hh[j];
    }
    compute_records_h(hh, lfW, lfb, lsW, lsb, D + (size_t)n*REC, Sh + (size_t)n*SHU);
}

// ---------------------------------------------------------------------------
// Layer-2 epilogue + pooling: segmented block-local reduction (batch sorted).
// ---------------------------------------------------------------------------
__global__ void node_pool(const float* __restrict__ h, const float* __restrict__ acc,
                          const int* __restrict__ batch,
                          float* __restrict__ gsum, float* __restrict__ gcnt, int N)
{
    __shared__ float lg[PBIN * DH];
    __shared__ float lc[PBIN];

    int base = blockIdx.x * blockDim.x;
    int n = base + threadIdx.x;

    for (int i = threadIdx.x; i < PBIN * DH; i += blockDim.x) lg[i] = 0.f;
    if (threadIdx.x < PBIN) lc[threadIdx.x] = 0.f;
    __syncthreads();

    int b0 = batch[base];   // uniform across block (sorted)

    if (n < N) {
        int b = batch[n];
        int off = b - b0;
        const float* hp = h + (size_t)n * DH;
        const float* ap = acc + (size_t)n * DH;
        float v[DH];
#pragma unroll
        for (int j = 0; j < DH; ++j) v[j] = fmaxf(hp[j] + ap[j], 0.f);

        if (off < PBIN) {
#pragma unroll
            for (int j = 0; j < DH; ++j) atomicAdd(&lg[off * DH + j], v[j]);
            atomicAdd(&lc[off], 1.f);
        } else {   // statistically impossible (256 sorted nodes span ~4 graphs)
            float* gp = gsum + (size_t)b * DH;
#pragma unroll
            for (int j = 0; j < DH; ++j) atomicAdd(gp + j, v[j]);
            atomicAdd(gcnt + b, 1.f);
        }
    }
    __syncthreads();

    for (int i = threadIdx.x; i < PBIN * DH; i += blockDim.x) {
        int g = i / DH;
        if (lc[g] > 0.f)
            atomicAdd(&gsum[(size_t)(b0 + g) * DH + (i - g * DH)], lg[i]);
    }
    if (threadIdx.x < PBIN && lc[threadIdx.x] > 0.f)
        atomicAdd(&gcnt[b0 + threadIdx.x], lc[threadIdx.x]);
}

// ---------------------------------------------------------------------------
// Fallback path kernels (fp32 atomic path; used only if ws too small / N too big)
// ---------------------------------------------------------------------------
__global__ void node_pre_f32(const float* __restrict__ x,
                             const float* __restrict__ preW, const float* __restrict__ preb,
                             const float* __restrict__ fW, const float* __restrict__ fb,
                             const float* __restrict__ sW, const float* __restrict__ sb,
                             float* __restrict__ h, float* __restrict__ D, float* __restrict__ S,
                             float* __restrict__ agg,
                             float* __restrict__ gsum, float* __restrict__ gcnt, int N, int G)
{
    __shared__ float lpW[30], lpb[10], lfW[230], lfb[10], lsW[230], lsb[10];
    for (int i = threadIdx.x; i < 30;  i += blockDim.x) lpW[i] = preW[i];
    for (int i = threadIdx.x; i < 10;  i += blockDim.x) { lpb[i] = preb[i]; lfb[i] = fb[i]; lsb[i] = sb[i]; }
    for (int i = threadIdx.x; i < 230; i += blockDim.x) { lfW[i] = fW[i]; lsW[i] = sW[i]; }
    __syncthreads();
    int n = blockIdx.x * blockDim.x + threadIdx.x;
    if (n < G * DH) gsum[n] = 0.f;
    if (n < G)      gcnt[n] = 0.f;
    if (n >= N) return;
    float x0 = x[(size_t)n*3], x1 = x[(size_t)n*3+1], x2 = x[(size_t)n*3+2];
    float hh[DH];
#pragma unroll
    for (int j = 0; j < DH; ++j)
        hh[j] = fmaxf(lpb[j] + x0*lpW[j*3] + x1*lpW[j*3+1] + x2*lpW[j*3+2], 0.f);
    float* hp = h + (size_t)n * DH;
    float* ap = agg + (size_t)n * DH;
#pragma unroll
    for (int j = 0; j < DH; ++j) { hp[j] = hh[j]; ap[j] = 0.f; }
    compute_records(hh, lfW, lfb, lsW, lsb, D + (size_t)n*REC, S + (size_t)n*REC);
}

__global__ void edge_pass(const int* __restrict__ ei, const float* __restrict__ attr,
                          const float* __restrict__ D, const float* __restrict__ S,
                          const float* __restrict__ Wf, const float* __restrict__ Ws,
                          float* __restrict__ agg, int E)
{
    __shared__ float wfe[30], wse[30];
    if (threadIdx.x < 30) {
        int j = threadIdx.x / 3, t = threadIdx.x % 3;
        wfe[threadIdx.x] = Wf[j*23 + 20 + t];
        wse[threadIdx.x] = Ws[j*23 + 20 + t];
    }
    __syncthreads();
    int e = blockIdx.x * blockDim.x + threadIdx.x;
    if (e >= E) return;
    int src = ei[e];
    int dst = ei[(size_t)E + e];
    const float* eap = attr + (size_t)e * DE;
    float ea0 = eap[0], ea1 = eap[1], ea2 = eap[2];
    float drec[REC], srec[REC];
    const float4* Dp = (const float4*)(D + (size_t)dst * REC);
    const float4* Sp = (const float4*)(S + (size_t)src * REC);
#pragma unroll
    for (int i = 0; i < 5; ++i) { ((float4*)drec)[i] = Dp[i]; ((float4*)srec)[i] = Sp[i]; }
    float* ap = agg + (size_t)dst * DH;
#pragma unroll
    for (int j = 0; j < DH; ++j) {
        float pf = drec[j]      + srec[j]      + ea0*wfe[j*3] + ea1*wfe[j*3+1] + ea2*wfe[j*3+2];
        float ps = drec[DH + j] + srec[DH + j] + ea0*wse[j*3] + ea1*wse[j*3+1] + ea2*wse[j*3+2];
        float sg = 1.0f / (1.0f + __expf(-pf));
        float sp = fmaxf(ps, 0.f) + log1pf(__expf(-fabsf(ps)));
        atomicAdd(ap + j, sg * sp);
    }
}

__global__ void node_mid(float* __restrict__ h, float* __restrict__ agg,
                         const float* __restrict__ fW, const float* __restrict__ fb,
                         const float* __restrict__ sW, const float* __restrict__ sb,
                         float* __restrict__ D, float* __restrict__ S, int N)
{
    __shared__ float lfW[230], lfb[10], lsW[230], lsb[10];
    for (int i = threadIdx.x; i < 230; i += blockDim.x) { lfW[i] = fW[i]; lsW[i] = sW[i]; }
    for (int i = threadIdx.x; i < 10;  i += blockDim.x) { lfb[i] = fb[i]; lsb[i] = sb[i]; }
    __syncthreads();
    int n = blockIdx.x * blockDim.x + threadIdx.x;
    if (n >= N) return;
    float* hp = h + (size_t)n * DH;
    float* ap = agg + (size_t)n * DH;
    float hh[DH];
#pragma unroll
    for (int j = 0; j < DH; ++j) {
        hh[j] = fmaxf(hp[j] + ap[j], 0.f);
        hp[j] = hh[j];
        ap[j] = 0.f;
    }
    compute_records(hh, lfW, lfb, lsW, lsb, D + (size_t)n*REC, S + (size_t)n*REC);
}

__global__ void node_post(const float* __restrict__ h, const float* __restrict__ agg,
                          const int* __restrict__ batch,
                          float* __restrict__ gsum, float* __restrict__ gcnt, int N)
{
    int n = blockIdx.x * blockDim.x + threadIdx.x;
    if (n >= N) return;
    int b = batch[n];
    const float* hp = h + (size_t)n * DH;
    const float* ap = agg + (size_t)n * DH;
    float* gp = gsum + (size_t)b * DH;
#pragma unroll
    for (int j = 0; j < DH; ++j)
        atomicAdd(gp + j, fmaxf(hp[j] + ap[j], 0.f));
    atomicAdd(gcnt + b, 1.f);
}

// ---------------------------------------------------------------------------
// MLP head: one block (128 threads) per graph.
// ---------------------------------------------------------------------------
__global__ void mlp_head(const float* __restrict__ gsum, const float* __restrict__ gcnt,
                         const float* __restrict__ fc1W, const float* __restrict__ fc1b,
                         const float* __restrict__ fc2W, const float* __restrict__ fc2b,
                         const float* __restrict__ outW, const float* __restrict__ outb,
                         float* __restrict__ out, int G)
{
    __shared__ float g[DH], a1[128], a2[128];
    int gid = blockIdx.x;
    int t = threadIdx.x;
    if (t < DH) {
        float c = fmaxf(gcnt[gid], 1.0f);
        g[t] = gsum[(size_t)gid*DH + t] / c;
    }
    __syncthreads();
    {
        float acc = fc1b[t];
        const float* w = fc1W + (size_t)t * DH;
#pragma unroll
        for (int k = 0; k < DH; ++k) acc += w[k] * g[k];
        a1[t] = fmaxf(acc, 0.f);
    }
    __syncthreads();
    {
        float acc = fc2b[t];
        const float* w = fc2W + (size_t)t * 128;
#pragma unroll 8
        for (int k = 0; k < 128; ++k) acc += w[k] * a1[k];
        a2[t] = fmaxf(acc, 0.f);
    }
    __syncthreads();
    if (t < 3) {
        float acc = outb[t];
        const float* w = outW + (size_t)t * 128;
#pragma unroll 8
        for (int k = 0; k < 128; ++k) acc += w[k] * a2[k];
        out[(size_t)gid*3 + t] = acc;
    }
}

// ---------------------------------------------------------------------------
extern "C" void kernel_launch(void* const* d_in, const int* in_sizes, int n_in,
                              void* d_out, int out_size, void* d_ws, size_t ws_size,
                              hipStream_t stream)
{
    const float* x     = (const float*)d_in[0];
    const int*   ei    = (const int*)  d_in[1];
    const float* attr  = (const float*)d_in[2];
    const int*   batch = (const int*)  d_in[3];
    const float* preW  = (const float*)d_in[4];
    const float* preb  = (const float*)d_in[5];
    const float* f1W   = (const float*)d_in[6];
    const float* f1b   = (const float*)d_in[7];
    const float* s1W   = (const float*)d_in[8];
    const float* s1b   = (const float*)d_in[9];
    const float* f2W   = (const float*)d_in[10];
    const float* f2b   = (const float*)d_in[11];
    const float* s2W   = (const float*)d_in[12];
    const float* s2b   = (const float*)d_in[13];
    const float* fc1W  = (const float*)d_in[14];
    const float* fc1b  = (const float*)d_in[15];
    const float* fc2W  = (const float*)d_in[16];
    const float* fc2b  = (const float*)d_in[17];
    const float* outW  = (const float*)d_in[18];
    const float* outb  = (const float*)d_in[19];

    const int N = in_sizes[0] / DIN;          // 200000
    const int E = in_sizes[1] / 2;            // 6400000
    const int G = out_size / 3;               // 1024
    const int M = NS * N;                     // bucket-head table size
    const int npw = (N + WGN - 1) / WGN;      // 157 dst nodes per persistent wg

    const int TB = 256;
    const int nb = (N + TB - 1) / TB;
    const int eb = (E + TB - 1) / TB;
    const int zb = ((M > G * DH ? M : G * DH) + TB - 1) / TB;

    // ---- workspace layout (csr capacity computed from remaining budget) ----
    size_t f_off = 0;
    float* ws = (float*)d_ws;
    float* h    = ws + f_off; f_off += (size_t)N * DH;
    float* D    = ws + f_off; f_off += (size_t)N * REC;
    f_off = (f_off + 15) & ~(size_t)15;                        // 64B-align Sh
    u32*   Sh   = (u32*)(ws + f_off); f_off += (size_t)N * SHU;
    float* acc  = ws + f_off; f_off += (size_t)N * DH;
    float* gsum = ws + f_off; f_off += (size_t)G * DH;
    float* gcnt = ws + f_off; f_off += G;
    f_off = (f_off + 15) & ~(size_t)15;
    int* heads  = (int*)(ws + f_off); f_off += M;
    int* ovfh   = (int*)(ws + f_off); f_off += 1;
    f_off = (f_off + 15) & ~(size_t)15;
    uint4* ovf  = (uint4*)(ws + f_off); f_off += (size_t)OVFCAP * 4;
    f_off = (f_off + 15) & ~(size_t)15;
    uint2* csr  = (uint2*)(ws + f_off);

    size_t core_bytes = f_off * sizeof(float);
    long long budget = (long long)ws_size - (long long)core_bytes;
    int cap = 0;
    if (budget > 0) cap = (int)(budget / ((long long)M * 8));
    if (cap > 16) cap = 16;

    if (cap >= 6 && npw <= MAXNPW && N < (1 << 18)) {
        // ===== capacity-bucket + persistent slice-walk path =====
        zero_small<<<zb, TB, 0, stream>>>(heads, M, ovfh, gsum, gcnt, G);
        node_pre_h<<<nb, TB, 0, stream>>>(x, preW, preb, f1W, f1b, s1W, s1b,
                                          h, D, Sh, N);
        scatter_cap<<<eb, TB, 0, stream>>>(ei, attr, heads, csr, ovf, ovfh, E, N, cap);

        gather_persist<<<WGN, 256, 0, stream>>>(heads, csr, cap, D, Sh,
                                                f1W, s1W, acc, N, npw);
        ovf_pass<<<256, 256, 0, stream>>>(ovf, ovfh, D, Sh, f1W, s1W, acc);
        node_mid_h<<<nb, TB, 0, stream>>>(h, acc, f2W, f2b, s2W, s2b, D, Sh, N);

        gather_persist<<<WGN, 256, 0, stream>>>(heads, csr, cap, D, Sh,
                                                f2W, s2W, acc, N, npw);
        ovf_pass<<<256, 256, 0, stream>>>(ovf, ovfh, D, Sh, f2W, s2W, acc);
        node_pool<<<nb, TB, 0, stream>>>(h, acc, batch, gsum, gcnt, N);
        mlp_head<<<G, 128, 0, stream>>>(gsum, gcnt, fc1W, fc1b, fc2W, fc2b,
                                        outW, outb, (float*)d_out, G);
    } else {
        // ===== fallback: fp32 atomic path =====
        size_t o = 0;
        float* fh    = ws + o; o += (size_t)N * DH;
        float* agg   = ws + o; o += (size_t)N * DH;
        float* fD    = ws + o; o += (size_t)N * REC;
        float* fS    = ws + o; o += (size_t)N * REC;
        float* fgsum = ws + o; o += (size_t)G * DH;
        float* fgcnt = ws + o; o += G;

        node_pre_f32<<<nb, TB, 0, stream>>>(x, preW, preb, f1W, f1b, s1W, s1b,
                                            fh, fD, fS, agg, fgsum, fgcnt, N, G);
        edge_pass<<<eb, TB, 0, stream>>>(ei, attr, fD, fS, f1W, s1W, agg, E);
        node_mid<<<nb, TB, 0, stream>>>(fh, agg, f2W, f2b, s2W, s2b, fD, fS, N);
        edge_pass<<<eb, TB, 0, stream>>>(ei, attr, fD, fS, f2W, s2W, agg, E);
        node_post<<<nb, TB, 0, stream>>>(fh, agg, batch, fgsum, fgcnt, N);
        mlp_head<<<G, 128, 0, stream>>>(fgsum, fgcnt, fc1W, fc1b, fc2W, fc2b,
                                        outW, outb, (float*)d_out, G);
    }
}